// Round 4
// baseline (271.168 us; speedup 1.0000x reference)
//
#include <hip/hip_runtime.h>

// Problem constants (from reference)
constexpr int N_SAMPLES = 512;
constexpr int J_GENES   = 20000;
constexpr int P_COV     = 8;
constexpr int DIM       = J_GENES - 1;     // pivot=True: last logit column is 0
constexpr int BLOCK     = 512;             // one block per row, 8 waves
constexpr int NW        = BLOCK / 64;      // waves per block
constexpr int UPB       = 10;              // units: 512 thr * 4 elem * 10 = 20480
constexpr int JPAD      = BLOCK * 4 * UPB; // 20480 padded gene count
constexpr int PREP_B    = 256;
constexpr int TABLE_N   = 1024;            // lgamma(y+1), y in [0,1000]

// ws layout (floats). 16B-aligned sections; padded tails are benign-filled.
constexpr size_t WS_RW    = 0;                               // r = 1/softplus(phi)   [JPAD]
constexpr size_t WS_MUP   = WS_RW    + JPAD;                 // mu padded             [JPAD]
constexpr size_t WS_BETAP = WS_MUP   + JPAD;                 // beta repacked [p][J]  [P*JPAD]
constexpr size_t WS_CVEC  = WS_BETAP + (size_t)P_COV * JPAD; // r*log r - lgamma(r)   [JPAD]
constexpr size_t WS_LGYT  = WS_CVEC  + JPAD;                 // lgamma(k+1) table     [TABLE_N]
constexpr size_t WS_TOTAL = WS_LGYT  + TABLE_N;              // floats

__device__ inline float wave_reduce_sum(float v) {
#pragma unroll
    for (int off = 32; off > 0; off >>= 1)
        v += __shfl_down(v, off, 64);
    return v;
}

// Stirling lgamma for z >= ~0.2. ~1e-6 rel accuracy (threshold is 2% of 1e8).
__device__ inline float lgamma_pos(float z) {
    float corr = 0.0f;
    if (z < 8.0f) {
        float p = z;
        p *= (z + 1.0f); p *= (z + 2.0f); p *= (z + 3.0f);
        p *= (z + 4.0f); p *= (z + 5.0f); p *= (z + 6.0f); p *= (z + 7.0f);
        corr = -__logf(p);
        z += 8.0f;
    }
    float lz  = __logf(z);
    float rz  = __builtin_amdgcn_rcpf(z);
    float rz2 = rz * rz;
    float ser = rz * fmaf(rz2, fmaf(rz2, 7.9365079365e-4f, -2.7777777778e-3f),
                          8.3333333333e-2f);
    return fmaf(z - 0.5f, lz, 0.91893853320467274f - z + ser + corr);
}

// ---------------------------------------------------------------------------
// Prep: per-gene tables + padded mu/beta repack + lgamma(y+1) table + out=0.
// ---------------------------------------------------------------------------
__global__ __launch_bounds__(PREP_B) void prep_kernel(
    const float* __restrict__ mu, const float* __restrict__ beta,
    const float* __restrict__ phi, float* __restrict__ ws,
    float* __restrict__ out) {
    const int gid = blockIdx.x * PREP_B + threadIdx.x;
    if (gid == 0) out[0] = 0.0f;
    if (gid < TABLE_N) ws[WS_LGYT + gid] = lgammaf((float)gid + 1.0f);
    if (gid >= JPAD) return;
    if (gid < J_GENES) {
        const int j = gid;
        float ph = phi[j];
        float sp = (ph > 20.0f) ? ph : log1pf(__expf(ph));  // softplus
        float r  = 1.0f / sp;
        ws[WS_RW   + j] = r;
        ws[WS_CVEC + j] = fmaf(r, -__logf(sp), -lgammaf(r)); // r*log r - lgamma(r)
        ws[WS_MUP  + j] = (j < DIM) ? mu[j] : 0.0f;          // pivot logit = 0
#pragma unroll
        for (int p = 0; p < P_COV; ++p)
            ws[WS_BETAP + (size_t)p * JPAD + j] =
                (j < DIM) ? beta[p * DIM + j] : 0.0f;
    } else {
        ws[WS_RW   + gid] = 1.0f;
        ws[WS_CVEC + gid] = 0.0f;
        ws[WS_MUP  + gid] = 0.0f;
#pragma unroll
        for (int p = 0; p < P_COV; ++p)
            ws[WS_BETAP + (size_t)p * JPAD + gid] = 0.0f;
    }
}

// ---------------------------------------------------------------------------
// Main: one 512-thread block per sample row. Phase A computes s = sum(Y) and
// E = sum(exp(logit)) while caching Y and logits in registers; phase B sums
// the collapsed NB log-pmf:
//   sum_j [ lgamma(y+r) - lgamma(y+1) - (y+r)*log(r+mean) + y*logit + cvec_j ]
//   + s*(log s - lse)            (per-row, since sum_j y_j = s)
// where cvec_j = r*log r - lgamma(r), mean = (s/E)*exp(logit).
// ---------------------------------------------------------------------------
__global__ __launch_bounds__(BLOCK, 4) void nb_main(
    const float* __restrict__ X, const float* __restrict__ Y,
    const float* __restrict__ ws, float* __restrict__ out) {

    const int n = blockIdx.x;
    const int t = threadIdx.x;

    __shared__ __align__(16) float tbl[TABLE_N];
    __shared__ float rs[NW], re[NW], red[NW];
    __shared__ float shv[2];   // s, E

    // lgamma(y+1) table into LDS (first 256 threads, float4 each)
    if (t * 4 < TABLE_N)
        *(float4*)&tbl[t * 4] = *(const float4*)(ws + WS_LGYT + t * 4);

    float x[P_COV];
#pragma unroll
    for (int p = 0; p < P_COV; ++p) x[p] = X[n * P_COV + p];

    const float* yrow = Y + (size_t)n * J_GENES;

    // ---- phase A: row sums, caching Y and logits ----
    float4 y_cache[UPB];
    float4 l_cache[UPB];
    float s_acc = 0.0f, e_acc = 0.0f;

#pragma unroll
    for (int u = 0; u < UPB; ++u) {
        const int j = u * (BLOCK * 4) + t * 4;
        float4 y4 = make_float4(0.f, 0.f, 0.f, 0.f);
        float4 lg = make_float4(0.f, 0.f, 0.f, 0.f);
        if (j < J_GENES) {
            y4 = *(const float4*)(yrow + j);
            lg = *(const float4*)(ws + WS_MUP + j);
#pragma unroll
            for (int p = 0; p < P_COV; ++p) {
                float4 bb = *(const float4*)(ws + WS_BETAP + (size_t)p * JPAD + j);
                lg.x = fmaf(x[p], bb.x, lg.x);
                lg.y = fmaf(x[p], bb.y, lg.y);
                lg.z = fmaf(x[p], bb.z, lg.z);
                lg.w = fmaf(x[p], bb.w, lg.w);
            }
            s_acc += (y4.x + y4.y) + (y4.z + y4.w);
            e_acc += (__expf(lg.x) + __expf(lg.y)) + (__expf(lg.z) + __expf(lg.w));
        }
        y_cache[u] = y4;
        l_cache[u] = lg;
    }

    {
        float vs = wave_reduce_sum(s_acc);
        float ve = wave_reduce_sum(e_acc);
        if ((t & 63) == 0) { rs[t >> 6] = vs; re[t >> 6] = ve; }
    }
    __syncthreads();
    if (t == 0) {
        float s = 0.f, E = 0.f;
#pragma unroll
        for (int w = 0; w < NW; ++w) { s += rs[w]; E += re[w]; }
        shv[0] = s; shv[1] = E;
    }
    __syncthreads();

    const float s    = shv[0];
    const float E    = shv[1];
    const float logs = __logf(s);
    const float lse  = __logf(E);
    const float sE   = s / E;           // mean = sE * exp(logit)

    // ---- phase B: NB log-likelihood ----
    float acc = 0.0f;
#pragma unroll
    for (int u = 0; u < UPB; ++u) {
        const int j = u * (BLOCK * 4) + t * 4;
        if (j < J_GENES) {
            float4 y4 = y_cache[u];
            float4 lg = l_cache[u];
            float4 r4 = *(const float4*)(ws + WS_RW   + j);
            float4 c4 = *(const float4*)(ws + WS_CVEC + j);
#pragma unroll
            for (int e = 0; e < 4; ++e) {
                float y     = (&y4.x)[e];
                float logit = (&lg.x)[e];
                float r     = (&r4.x)[e];
                float cv    = (&c4.x)[e];
                float mean  = sE * __expf(logit);
                float lrm   = __logf(r + mean);
                int   yi    = (int)(y + 0.5f);
                float lgy1  = (yi < TABLE_N) ? tbl[yi] : lgamma_pos(y + 1.0f);
                acc += lgamma_pos(y + r) - lgy1
                     + fmaf(-(y + r), lrm, fmaf(y, logit, cv));
            }
        }
    }

    if (t == 0) acc += s * (logs - lse);   // per-row closed-form term

    {
        float v = wave_reduce_sum(acc);
        if ((t & 63) == 0) red[t >> 6] = v;
        __syncthreads();
        if (t == 0) {
            float b = 0.f;
#pragma unroll
            for (int w = 0; w < NW; ++w) b += red[w];
            atomicAdd(out, b);
        }
    }
}

// ---------------------------------------------------------------------------
// Fallback (ws too small): monolithic known-correct kernel, no workspace.
// ---------------------------------------------------------------------------
__global__ __launch_bounds__(256) void nb_mono(
    const float* __restrict__ mu, const float* __restrict__ beta,
    const float* __restrict__ phi, const float* __restrict__ X,
    const float* __restrict__ Y, float* __restrict__ out) {
    const int n = blockIdx.x;
    const int t = threadIdx.x;
    __shared__ float red[4];
    __shared__ float sh_s, sh_lse, sh_logs;
    float x[P_COV];
#pragma unroll
    for (int p = 0; p < P_COV; ++p) x[p] = X[n * P_COV + p];
    const float* yrow = Y + (size_t)n * J_GENES;
    float s_acc = 0.0f, e_acc = 0.0f;
    for (int j = t; j < J_GENES; j += 256) {
        float logit = 0.0f;
        if (j < DIM) {
            logit = mu[j];
#pragma unroll
            for (int p = 0; p < P_COV; ++p)
                logit = fmaf(x[p], beta[p * DIM + j], logit);
        }
        s_acc += yrow[j];
        e_acc += __expf(logit);
    }
    float v = wave_reduce_sum(s_acc);
    if ((t & 63) == 0) red[t >> 6] = v;
    __syncthreads();
    if (t == 0) { float st = red[0]+red[1]+red[2]+red[3]; sh_s = st; sh_logs = __logf(st); }
    __syncthreads();
    v = wave_reduce_sum(e_acc);
    if ((t & 63) == 0) red[t >> 6] = v;
    __syncthreads();
    if (t == 0) sh_lse = __logf(red[0]+red[1]+red[2]+red[3]);
    __syncthreads();
    const float s = sh_s, logs = sh_logs, lse = sh_lse;
    float acc = 0.0f;
    for (int j = t; j < J_GENES; j += 256) {
        float logit = 0.0f;
        if (j < DIM) {
            logit = mu[j];
#pragma unroll
            for (int p = 0; p < P_COV; ++p)
                logit = fmaf(x[p], beta[p * DIM + j], logit);
        }
        float ph = phi[j];
        float sp = (ph > 20.0f) ? ph : log1pf(__expf(ph));
        float r  = 1.0f / sp;
        float y  = yrow[j];
        float lp = logit - lse;
        float mean = s * __expf(lp);
        float lrm  = __logf(r + mean);
        acc += lgamma_pos(y + r) - lgamma_pos(r) - lgamma_pos(y + 1.0f)
             + fmaf(r, -__logf(sp) - lrm, y * ((logs + lp) - lrm));
    }
    v = wave_reduce_sum(acc);
    if ((t & 63) == 0) red[t >> 6] = v;
    __syncthreads();
    if (t == 0) atomicAdd(out, (red[0]+red[1])+(red[2]+red[3]));
}

__global__ void zero_out_kernel(float* __restrict__ out) { out[0] = 0.0f; }

// ---------------------------------------------------------------------------
extern "C" void kernel_launch(void* const* d_in, const int* in_sizes, int n_in,
                              void* d_out, int out_size, void* d_ws, size_t ws_size,
                              hipStream_t stream) {
    const float* mu   = (const float*)d_in[0];  // [DIM]
    const float* beta = (const float*)d_in[1];  // [P*DIM]
    const float* phi  = (const float*)d_in[2];  // [J]
    const float* X    = (const float*)d_in[3];  // [N,P]
    const float* Y    = (const float*)d_in[4];  // [N,J]
    float* out = (float*)d_out;
    float* ws  = (float*)d_ws;

    if (ws_size >= WS_TOTAL * sizeof(float)) {
        prep_kernel<<<JPAD / PREP_B, PREP_B, 0, stream>>>(mu, beta, phi, ws, out);
        nb_main<<<N_SAMPLES, BLOCK, 0, stream>>>(X, Y, ws, out);
    } else {
        zero_out_kernel<<<1, 1, 0, stream>>>(out);
        nb_mono<<<N_SAMPLES, 256, 0, stream>>>(mu, beta, phi, X, Y, out);
    }
}

// Round 5
// 179.332 us; speedup vs baseline: 1.5121x; 1.5121x over previous
//
#include <hip/hip_runtime.h>
#include <hip/hip_fp16.h>

// Problem constants (from reference)
constexpr int N_SAMPLES = 512;
constexpr int J_GENES   = 20000;
constexpr int P_COV     = 8;
constexpr int DIM       = J_GENES - 1;     // pivot=True: last logit column is 0
constexpr int BLOCK     = 512;             // one block per row, 8 waves
constexpr int NW        = BLOCK / 64;      // waves per block
constexpr int UPB       = 10;              // 512 thr * 4 elem * 10 = 20480
constexpr int JPAD      = BLOCK * 4 * UPB; // 20480 padded gene count
constexpr int PREP_B    = 256;
constexpr int TABLE_N   = 1024;            // lgamma(y+1), y in [0,1000]

// ws layout (floats). Padded tails benign-filled by prep.
constexpr size_t WS_RW    = 0;                               // r = 1/softplus(phi)   [JPAD]
constexpr size_t WS_MUP   = WS_RW    + JPAD;                 // mu padded             [JPAD]
constexpr size_t WS_BETAP = WS_MUP   + JPAD;                 // beta repacked [p][J]  [P*JPAD]
constexpr size_t WS_CVEC  = WS_BETAP + (size_t)P_COV * JPAD; // r*log r - lgamma(r)   [JPAD]
constexpr size_t WS_LGYT  = WS_CVEC  + JPAD;                 // lgamma(k+1) table     [TABLE_N]
constexpr size_t WS_TOTAL = WS_LGYT  + TABLE_N;              // floats

__device__ inline float wave_reduce_sum(float v) {
#pragma unroll
    for (int off = 32; off > 0; off >>= 1)
        v += __shfl_down(v, off, 64);
    return v;
}

// Stirling lgamma for z >= ~0.2. ~1e-6 rel accuracy (threshold is 2% of 1e8).
__device__ inline float lgamma_pos(float z) {
    float corr = 0.0f;
    if (z < 8.0f) {
        float p = z;
        p *= (z + 1.0f); p *= (z + 2.0f); p *= (z + 3.0f);
        p *= (z + 4.0f); p *= (z + 5.0f); p *= (z + 6.0f); p *= (z + 7.0f);
        corr = -__logf(p);
        z += 8.0f;
    }
    float lz  = __logf(z);
    float rz  = __builtin_amdgcn_rcpf(z);
    float rz2 = rz * rz;
    float ser = rz * fmaf(rz2, fmaf(rz2, 7.9365079365e-4f, -2.7777777778e-3f),
                          8.3333333333e-2f);
    return fmaf(z - 0.5f, lz, 0.91893853320467274f - z + ser + corr);
}

// ---------------------------------------------------------------------------
// Prep: per-gene tables + padded mu/beta repack + lgamma(y+1) table + out=0.
// ---------------------------------------------------------------------------
__global__ __launch_bounds__(PREP_B) void prep_kernel(
    const float* __restrict__ mu, const float* __restrict__ beta,
    const float* __restrict__ phi, float* __restrict__ ws,
    float* __restrict__ out) {
    const int gid = blockIdx.x * PREP_B + threadIdx.x;
    if (gid == 0) out[0] = 0.0f;
    if (gid < TABLE_N) ws[WS_LGYT + gid] = lgammaf((float)gid + 1.0f);
    if (gid >= JPAD) return;
    if (gid < J_GENES) {
        const int j = gid;
        float ph = phi[j];
        float sp = (ph > 20.0f) ? ph : log1pf(__expf(ph));  // softplus
        float r  = 1.0f / sp;
        ws[WS_RW   + j] = r;
        ws[WS_CVEC + j] = fmaf(r, -__logf(sp), -lgammaf(r)); // r*log r - lgamma(r)
        ws[WS_MUP  + j] = (j < DIM) ? mu[j] : 0.0f;          // pivot logit = 0
#pragma unroll
        for (int p = 0; p < P_COV; ++p)
            ws[WS_BETAP + (size_t)p * JPAD + j] =
                (j < DIM) ? beta[p * DIM + j] : 0.0f;
    } else {
        ws[WS_RW   + gid] = 1.0f;
        ws[WS_CVEC + gid] = 0.0f;
        ws[WS_MUP  + gid] = 0.0f;
#pragma unroll
        for (int p = 0; p < P_COV; ++p)
            ws[WS_BETAP + (size_t)p * JPAD + gid] = 0.0f;
    }
}

// ---------------------------------------------------------------------------
// Main: one 512-thread block per row.
//   Phase A: logits (from padded mu/beta), stored fp16 in LDS; s=sum(Y),
//            E=sum(exp(logit)).
//   Phase B: sum_j [ lgamma(y+r) - lgamma(y+1) - (y+r)*log(r+mean) + y*logit ]
//            + s*(log s - lse)                     (per-row)
//   Block 0 adds N * sum_j cvec_j,  cvec = r*log r - lgamma(r).
//   mean = (s/E)*exp(logit).
// ---------------------------------------------------------------------------
__global__ __launch_bounds__(BLOCK, 4) void nb_main(
    const float* __restrict__ X, const float* __restrict__ Y,
    const float* __restrict__ ws, float* __restrict__ out) {

    const int n = blockIdx.x;
    const int t = threadIdx.x;

    __shared__ __align__(16) __half lgs[JPAD];   // 40 KB logit cache
    __shared__ __align__(16) float tbl[TABLE_N]; // 4 KB
    __shared__ float rs[NW], re[NW], red[NW];
    __shared__ float shv[2];   // s, E

    // lgamma(y+1) table into LDS (first 256 threads, float4 each)
    if (t * 4 < TABLE_N)
        *(float4*)&tbl[t * 4] = *(const float4*)(ws + WS_LGYT + t * 4);

    float x[P_COV];
#pragma unroll
    for (int p = 0; p < P_COV; ++p) x[p] = X[n * P_COV + p];

    const float* yrow = Y + (size_t)n * J_GENES;

    // ---- phase A: logits -> LDS (fp16), row sums ----
    float s_acc = 0.0f, e_acc = 0.0f;
#pragma unroll
    for (int u = 0; u < UPB; ++u) {
        const int j = u * (BLOCK * 4) + t * 4;
        if (j < J_GENES) {
            float4 y4 = *(const float4*)(yrow + j);
            float4 lg = *(const float4*)(ws + WS_MUP + j);
#pragma unroll
            for (int p = 0; p < P_COV; ++p) {
                float4 bb = *(const float4*)(ws + WS_BETAP + (size_t)p * JPAD + j);
                lg.x = fmaf(x[p], bb.x, lg.x);
                lg.y = fmaf(x[p], bb.y, lg.y);
                lg.z = fmaf(x[p], bb.z, lg.z);
                lg.w = fmaf(x[p], bb.w, lg.w);
            }
            s_acc += (y4.x + y4.y) + (y4.z + y4.w);
            e_acc += (__expf(lg.x) + __expf(lg.y)) + (__expf(lg.z) + __expf(lg.w));
            __half2* dst = (__half2*)&lgs[j];
            dst[0] = __floats2half2_rn(lg.x, lg.y);
            dst[1] = __floats2half2_rn(lg.z, lg.w);
        }
    }

    {
        float vs = wave_reduce_sum(s_acc);
        float ve = wave_reduce_sum(e_acc);
        if ((t & 63) == 0) { rs[t >> 6] = vs; re[t >> 6] = ve; }
    }
    __syncthreads();
    if (t == 0) {
        float s = 0.f, E = 0.f;
#pragma unroll
        for (int w = 0; w < NW; ++w) { s += rs[w]; E += re[w]; }
        shv[0] = s; shv[1] = E;
    }
    __syncthreads();

    const float s    = shv[0];
    const float E    = shv[1];
    const float sE   = s / E;           // mean = sE * exp(logit)

    // ---- phase B: NB log-likelihood ----
    float acc = 0.0f;
#pragma unroll
    for (int u = 0; u < UPB; ++u) {
        const int j = u * (BLOCK * 4) + t * 4;
        if (j < J_GENES) {
            float4 y4 = *(const float4*)(yrow + j);     // L3-resident re-read
            float4 r4 = *(const float4*)(ws + WS_RW + j);
            const __half2* src = (const __half2*)&lgs[j];
            float2 l01 = __half22float2(src[0]);
            float2 l23 = __half22float2(src[1]);
            float lgv[4] = {l01.x, l01.y, l23.x, l23.y};
#pragma unroll
            for (int e = 0; e < 4; ++e) {
                float y     = (&y4.x)[e];
                float logit = lgv[e];
                float r     = (&r4.x)[e];
                float mean  = sE * __expf(logit);
                float lrm   = __logf(r + mean);
                int   yi    = (int)(y + 0.5f);
                acc += lgamma_pos(y + r) - tbl[yi]
                     + fmaf(-(y + r), lrm, y * logit);
            }
        }
    }

    if (t == 0) acc += s * (__logf(s) - __logf(E));  // per-row closed form

    // global constant N * sum_j cvec_j — block 0 only (80 KB L2 read, once)
    if (n == 0) {
        float cacc = 0.0f;
        for (int i = t; i < J_GENES; i += BLOCK) cacc += ws[WS_CVEC + i];
        acc += (float)N_SAMPLES * cacc;
    }

    {
        float v = wave_reduce_sum(acc);
        if ((t & 63) == 0) red[t >> 6] = v;
        __syncthreads();
        if (t == 0) {
            float b = 0.f;
#pragma unroll
            for (int w = 0; w < NW; ++w) b += red[w];
            atomicAdd(out, b);
        }
    }
}

// ---------------------------------------------------------------------------
// Fallback (ws too small): monolithic known-correct kernel, no workspace.
// ---------------------------------------------------------------------------
__global__ __launch_bounds__(256) void nb_mono(
    const float* __restrict__ mu, const float* __restrict__ beta,
    const float* __restrict__ phi, const float* __restrict__ X,
    const float* __restrict__ Y, float* __restrict__ out) {
    const int n = blockIdx.x;
    const int t = threadIdx.x;
    __shared__ float red[4];
    __shared__ float sh_s, sh_lse, sh_logs;
    float x[P_COV];
#pragma unroll
    for (int p = 0; p < P_COV; ++p) x[p] = X[n * P_COV + p];
    const float* yrow = Y + (size_t)n * J_GENES;
    float s_acc = 0.0f, e_acc = 0.0f;
    for (int j = t; j < J_GENES; j += 256) {
        float logit = 0.0f;
        if (j < DIM) {
            logit = mu[j];
#pragma unroll
            for (int p = 0; p < P_COV; ++p)
                logit = fmaf(x[p], beta[p * DIM + j], logit);
        }
        s_acc += yrow[j];
        e_acc += __expf(logit);
    }
    float v = wave_reduce_sum(s_acc);
    if ((t & 63) == 0) red[t >> 6] = v;
    __syncthreads();
    if (t == 0) { float st = red[0]+red[1]+red[2]+red[3]; sh_s = st; sh_logs = __logf(st); }
    __syncthreads();
    v = wave_reduce_sum(e_acc);
    if ((t & 63) == 0) red[t >> 6] = v;
    __syncthreads();
    if (t == 0) sh_lse = __logf(red[0]+red[1]+red[2]+red[3]);
    __syncthreads();
    const float s = sh_s, logs = sh_logs, lse = sh_lse;
    float acc = 0.0f;
    for (int j = t; j < J_GENES; j += 256) {
        float logit = 0.0f;
        if (j < DIM) {
            logit = mu[j];
#pragma unroll
            for (int p = 0; p < P_COV; ++p)
                logit = fmaf(x[p], beta[p * DIM + j], logit);
        }
        float ph = phi[j];
        float sp = (ph > 20.0f) ? ph : log1pf(__expf(ph));
        float r  = 1.0f / sp;
        float y  = yrow[j];
        float lp = logit - lse;
        float mean = s * __expf(lp);
        float lrm  = __logf(r + mean);
        acc += lgamma_pos(y + r) - lgamma_pos(r) - lgamma_pos(y + 1.0f)
             + fmaf(r, -__logf(sp) - lrm, y * ((logs + lp) - lrm));
    }
    v = wave_reduce_sum(acc);
    if ((t & 63) == 0) red[t >> 6] = v;
    __syncthreads();
    if (t == 0) atomicAdd(out, (red[0]+red[1])+(red[2]+red[3]));
}

__global__ void zero_out_kernel(float* __restrict__ out) { out[0] = 0.0f; }

// ---------------------------------------------------------------------------
extern "C" void kernel_launch(void* const* d_in, const int* in_sizes, int n_in,
                              void* d_out, int out_size, void* d_ws, size_t ws_size,
                              hipStream_t stream) {
    const float* mu   = (const float*)d_in[0];  // [DIM]
    const float* beta = (const float*)d_in[1];  // [P*DIM]
    const float* phi  = (const float*)d_in[2];  // [J]
    const float* X    = (const float*)d_in[3];  // [N,P]
    const float* Y    = (const float*)d_in[4];  // [N,J]
    float* out = (float*)d_out;
    float* ws  = (float*)d_ws;

    if (ws_size >= WS_TOTAL * sizeof(float)) {
        prep_kernel<<<JPAD / PREP_B, PREP_B, 0, stream>>>(mu, beta, phi, ws, out);
        nb_main<<<N_SAMPLES, BLOCK, 0, stream>>>(X, Y, ws, out);
    } else {
        zero_out_kernel<<<1, 1, 0, stream>>>(out);
        nb_mono<<<N_SAMPLES, 256, 0, stream>>>(mu, beta, phi, X, Y, out);
    }
}

// Round 6
// 153.048 us; speedup vs baseline: 1.7718x; 1.1717x over previous
//
#include <hip/hip_runtime.h>

// Problem constants (from reference)
constexpr int N_SAMPLES = 512;
constexpr int J_GENES   = 20000;
constexpr int P_COV     = 8;
constexpr int DIM       = J_GENES - 1;   // pivot=True: logit[19999] = 0 (mu/beta padded w/ 0)
constexpr int BLOCK     = 256;
constexpr int NW        = BLOCK / 64;
constexpr int CHUNK     = 2048;          // genes per block: 256 thr x 4 elem x 2 groups
constexpr int NBJ       = 10;            // chunks per row (10*2048 = 20480 >= 20000)
constexpr int JPAD      = NBJ * CHUNK;   // 20480
constexpr int NPART     = NBJ * N_SAMPLES; // 5120 per-block partials
constexpr int TABLE_N   = 1024;          // lgamma(y+1), y in [0,1000]

// ws layout (floats)
constexpr size_t WS_RW    = 0;                               // r = 1/softplus(phi)  [JPAD]
constexpr size_t WS_MUP   = WS_RW    + JPAD;                 // mu padded            [JPAD]
constexpr size_t WS_BETAP = WS_MUP   + JPAD;                 // beta repacked [p][J] [P*JPAD]
constexpr size_t WS_CVEC  = WS_BETAP + (size_t)P_COV * JPAD; // r*log r - lgamma(r)  [JPAD]
constexpr size_t WS_LGYT  = WS_CVEC  + JPAD;                 // lgamma(k+1) table    [TABLE_N]
constexpr size_t WS_SACC  = WS_LGYT  + TABLE_N;              // per-row sum(Y)       [N]
constexpr size_t WS_EACC  = WS_SACC  + N_SAMPLES;            // per-row sum(exp)     [N]
constexpr size_t WS_PART  = WS_EACC  + N_SAMPLES;            // loglik partials      [NPART]
constexpr size_t WS_TOTAL = WS_PART  + NPART;                // floats

__device__ inline float wave_reduce_sum(float v) {
#pragma unroll
    for (int off = 32; off > 0; off >>= 1)
        v += __shfl_down(v, off, 64);
    return v;
}

__device__ inline float block_reduce_sum(float v, float* red) {
    const int t = threadIdx.x;
    float w = wave_reduce_sum(v);
    if ((t & 63) == 0) red[t >> 6] = w;
    __syncthreads();
    float b = 0.0f;
#pragma unroll
    for (int i = 0; i < NW; ++i) b += red[i];
    return b;   // valid in all threads
}

// Stirling lgamma for z >= ~0.2. ~1e-6 rel accuracy (threshold is 2% of 1e8).
__device__ inline float lgamma_pos(float z) {
    float corr = 0.0f;
    if (z < 8.0f) {
        float p = z;
        p *= (z + 1.0f); p *= (z + 2.0f); p *= (z + 3.0f);
        p *= (z + 4.0f); p *= (z + 5.0f); p *= (z + 6.0f); p *= (z + 7.0f);
        corr = -__logf(p);
        z += 8.0f;
    }
    float lz  = __logf(z);
    float rz  = __builtin_amdgcn_rcpf(z);
    float rz2 = rz * rz;
    float ser = rz * fmaf(rz2, fmaf(rz2, 7.9365079365e-4f, -2.7777777778e-3f),
                          8.3333333333e-2f);
    return fmaf(z - 0.5f, lz, 0.91893853320467274f - z + ser + corr);
}

// Compute the 4 logits for gene group j (j multiple of 4, j+3 < JPAD).
__device__ inline float4 logits4(const float* __restrict__ ws,
                                 const float* __restrict__ x, int j) {
    float4 lg = *(const float4*)(ws + WS_MUP + j);
#pragma unroll
    for (int p = 0; p < P_COV; ++p) {
        float4 bb = *(const float4*)(ws + WS_BETAP + (size_t)p * JPAD + j);
        lg.x = fmaf(x[p], bb.x, lg.x);
        lg.y = fmaf(x[p], bb.y, lg.y);
        lg.z = fmaf(x[p], bb.z, lg.z);
        lg.w = fmaf(x[p], bb.w, lg.w);
    }
    return lg;
}

// ---------------------------------------------------------------------------
// Prep: padded repack + per-gene tables + zero s/E accumulators.
// ---------------------------------------------------------------------------
__global__ __launch_bounds__(BLOCK) void prep_kernel(
    const float* __restrict__ mu, const float* __restrict__ beta,
    const float* __restrict__ phi, float* __restrict__ ws) {
    const int gid = blockIdx.x * BLOCK + threadIdx.x;
    if (gid < TABLE_N) ws[WS_LGYT + gid] = lgammaf((float)gid + 1.0f);
    if (gid < N_SAMPLES) { ws[WS_SACC + gid] = 0.0f; ws[WS_EACC + gid] = 0.0f; }
    if (gid >= JPAD) return;
    if (gid < J_GENES) {
        const int j = gid;
        float ph = phi[j];
        float sp = (ph > 20.0f) ? ph : log1pf(__expf(ph));   // softplus
        float r  = 1.0f / sp;
        ws[WS_RW   + j] = r;
        ws[WS_CVEC + j] = fmaf(r, -__logf(sp), -lgammaf(r)); // r*log r - lgamma(r)
        ws[WS_MUP  + j] = (j < DIM) ? mu[j] : 0.0f;          // pivot logit = 0
#pragma unroll
        for (int p = 0; p < P_COV; ++p)
            ws[WS_BETAP + (size_t)p * JPAD + j] =
                (j < DIM) ? beta[p * DIM + j] : 0.0f;
    } else {
        ws[WS_RW   + gid] = 1.0f;
        ws[WS_CVEC + gid] = 0.0f;
        ws[WS_MUP  + gid] = 0.0f;
#pragma unroll
        for (int p = 0; p < P_COV; ++p)
            ws[WS_BETAP + (size_t)p * JPAD + gid] = 0.0f;
    }
}

// ---------------------------------------------------------------------------
// Pass 1: s[n] = sum_j Y, E[n] = sum_j exp(logit). grid (NBJ, N).
// ---------------------------------------------------------------------------
__global__ __launch_bounds__(BLOCK) void rowsum_kernel(
    const float* __restrict__ X, const float* __restrict__ Y,
    float* __restrict__ ws) {
    const int n = blockIdx.y;
    const int t = threadIdx.x;
    const int j0 = blockIdx.x * CHUNK + t * 4;

    float x[P_COV];
#pragma unroll
    for (int p = 0; p < P_COV; ++p) x[p] = X[n * P_COV + p];
    const float* yrow = Y + (size_t)n * J_GENES;

    float s_acc = 0.0f, e_acc = 0.0f;
    // two groups, strictly sequential (small live set -> no spill)
    for (int g = 0; g < 2; ++g) {
        const int j = j0 + g * (BLOCK * 4);
        if (j < J_GENES) {
            float4 y4 = *(const float4*)(yrow + j);
            float4 lg = logits4(ws, x, j);
            s_acc += (y4.x + y4.y) + (y4.z + y4.w);
            e_acc += (__expf(lg.x) + __expf(lg.y)) + (__expf(lg.z) + __expf(lg.w));
        }
    }

    __shared__ float red[NW];
    float s = block_reduce_sum(s_acc, red);
    __syncthreads();
    float e = block_reduce_sum(e_acc, red);
    if (t == 0) {
        atomicAdd(&ws[WS_SACC + n], s);
        atomicAdd(&ws[WS_EACC + n], e);
    }
}

// ---------------------------------------------------------------------------
// Pass 2: per-block NB log-lik partial. grid (NBJ, N).
//   sum_j [ lgamma(y+r) - lgamma(y+1) - (y+r)*log(r+mean) + y*logit ]
// (cvec and per-row closed-form terms added in final_kernel)
// ---------------------------------------------------------------------------
__global__ __launch_bounds__(BLOCK) void loglik_kernel(
    const float* __restrict__ X, const float* __restrict__ Y,
    float* __restrict__ ws) {
    const int n = blockIdx.y;
    const int t = threadIdx.x;
    const int j0 = blockIdx.x * CHUNK + t * 4;

    __shared__ __align__(16) float tbl[TABLE_N];
    *(float4*)&tbl[t * 4] = *(const float4*)(ws + WS_LGYT + t * 4);

    float x[P_COV];
#pragma unroll
    for (int p = 0; p < P_COV; ++p) x[p] = X[n * P_COV + p];
    const float* yrow = Y + (size_t)n * J_GENES;

    const float s  = ws[WS_SACC + n];
    const float E  = ws[WS_EACC + n];
    const float sE = s / E;          // mean = sE * exp(logit)
    __syncthreads();                 // tbl ready

    float acc = 0.0f;
    for (int g = 0; g < 2; ++g) {
        const int j = j0 + g * (BLOCK * 4);
        if (j < J_GENES) {
            float4 y4 = *(const float4*)(yrow + j);
            float4 r4 = *(const float4*)(ws + WS_RW + j);
            float4 lg = logits4(ws, x, j);
#pragma unroll
            for (int e = 0; e < 4; ++e) {
                float y     = (&y4.x)[e];
                float r     = (&r4.x)[e];
                float logit = (&lg.x)[e];
                float mean  = sE * __expf(logit);
                float lrm   = __logf(r + mean);
                int   yi    = (int)(y + 0.5f);
                float lgy1  = (yi < TABLE_N) ? tbl[yi] : lgamma_pos(y + 1.0f);
                acc += lgamma_pos(y + r) - lgy1
                     + fmaf(-(y + r), lrm, y * logit);
            }
        }
    }

    __shared__ float red[NW];
    float b = block_reduce_sum(acc, red);
    if (t == 0) ws[WS_PART + (size_t)n * NBJ + blockIdx.x] = b;
}

// ---------------------------------------------------------------------------
// Final: out = sum(partials) + sum_n s_n*(log s_n - log E_n) + N * sum_j cvec.
// ---------------------------------------------------------------------------
__global__ __launch_bounds__(BLOCK) void final_kernel(
    const float* __restrict__ ws, float* __restrict__ out) {
    const int t = threadIdx.x;
    float acc = 0.0f;
    for (int i = t; i < NPART; i += BLOCK) acc += ws[WS_PART + i];
    for (int n = t; n < N_SAMPLES; n += BLOCK) {
        float s = ws[WS_SACC + n];
        float E = ws[WS_EACC + n];
        acc += s * (__logf(s) - __logf(E));
    }
    float cacc = 0.0f;
    for (int i = t; i < J_GENES; i += BLOCK) cacc += ws[WS_CVEC + i];
    acc += (float)N_SAMPLES * cacc;

    __shared__ float red[NW];
    float b = block_reduce_sum(acc, red);
    if (t == 0) out[0] = b;
}

// ---------------------------------------------------------------------------
// Fallback (ws too small): monolithic known-correct kernel, no workspace.
// ---------------------------------------------------------------------------
__global__ __launch_bounds__(256) void nb_mono(
    const float* __restrict__ mu, const float* __restrict__ beta,
    const float* __restrict__ phi, const float* __restrict__ X,
    const float* __restrict__ Y, float* __restrict__ out) {
    const int n = blockIdx.x;
    const int t = threadIdx.x;
    __shared__ float red[4];
    __shared__ float sh_s, sh_lse, sh_logs;
    float x[P_COV];
#pragma unroll
    for (int p = 0; p < P_COV; ++p) x[p] = X[n * P_COV + p];
    const float* yrow = Y + (size_t)n * J_GENES;
    float s_acc = 0.0f, e_acc = 0.0f;
    for (int j = t; j < J_GENES; j += 256) {
        float logit = 0.0f;
        if (j < DIM) {
            logit = mu[j];
#pragma unroll
            for (int p = 0; p < P_COV; ++p)
                logit = fmaf(x[p], beta[p * DIM + j], logit);
        }
        s_acc += yrow[j];
        e_acc += __expf(logit);
    }
    float v = wave_reduce_sum(s_acc);
    if ((t & 63) == 0) red[t >> 6] = v;
    __syncthreads();
    if (t == 0) { float st = red[0]+red[1]+red[2]+red[3]; sh_s = st; sh_logs = __logf(st); }
    __syncthreads();
    v = wave_reduce_sum(e_acc);
    if ((t & 63) == 0) red[t >> 6] = v;
    __syncthreads();
    if (t == 0) sh_lse = __logf(red[0]+red[1]+red[2]+red[3]);
    __syncthreads();
    const float s = sh_s, logs = sh_logs, lse = sh_lse;
    float acc = 0.0f;
    for (int j = t; j < J_GENES; j += 256) {
        float logit = 0.0f;
        if (j < DIM) {
            logit = mu[j];
#pragma unroll
            for (int p = 0; p < P_COV; ++p)
                logit = fmaf(x[p], beta[p * DIM + j], logit);
        }
        float ph = phi[j];
        float sp = (ph > 20.0f) ? ph : log1pf(__expf(ph));
        float r  = 1.0f / sp;
        float y  = yrow[j];
        float lp = logit - lse;
        float mean = s * __expf(lp);
        float lrm  = __logf(r + mean);
        acc += lgamma_pos(y + r) - lgamma_pos(r) - lgamma_pos(y + 1.0f)
             + fmaf(r, -__logf(sp) - lrm, y * ((logs + lp) - lrm));
    }
    v = wave_reduce_sum(acc);
    if ((t & 63) == 0) red[t >> 6] = v;
    __syncthreads();
    if (t == 0) atomicAdd(out, (red[0]+red[1])+(red[2]+red[3]));
}

__global__ void zero_out_kernel(float* __restrict__ out) { out[0] = 0.0f; }

// ---------------------------------------------------------------------------
extern "C" void kernel_launch(void* const* d_in, const int* in_sizes, int n_in,
                              void* d_out, int out_size, void* d_ws, size_t ws_size,
                              hipStream_t stream) {
    const float* mu   = (const float*)d_in[0];  // [DIM]
    const float* beta = (const float*)d_in[1];  // [P*DIM]
    const float* phi  = (const float*)d_in[2];  // [J]
    const float* X    = (const float*)d_in[3];  // [N,P]
    const float* Y    = (const float*)d_in[4];  // [N,J]
    float* out = (float*)d_out;
    float* ws  = (float*)d_ws;

    if (ws_size >= WS_TOTAL * sizeof(float)) {
        dim3 grid(NBJ, N_SAMPLES);
        prep_kernel<<<JPAD / BLOCK, BLOCK, 0, stream>>>(mu, beta, phi, ws);
        rowsum_kernel<<<grid, BLOCK, 0, stream>>>(X, Y, ws);
        loglik_kernel<<<grid, BLOCK, 0, stream>>>(X, Y, ws);
        final_kernel<<<1, BLOCK, 0, stream>>>(ws, out);
    } else {
        zero_out_kernel<<<1, 1, 0, stream>>>(out);
        nb_mono<<<N_SAMPLES, 256, 0, stream>>>(mu, beta, phi, X, Y, out);
    }
}

// Round 7
// 150.790 us; speedup vs baseline: 1.7983x; 1.0150x over previous
//
#include <hip/hip_runtime.h>
#include <hip/hip_fp16.h>

// Problem constants (from reference)
constexpr int N_SAMPLES = 512;
constexpr int J_GENES   = 20000;
constexpr int P_COV     = 8;
constexpr int DIM       = J_GENES - 1;   // pivot=True: logit[19999] = 0 (mu/beta padded w/ 0)
constexpr int BLOCK     = 256;
constexpr int NW        = BLOCK / 64;

// logitE tiling: 640 blocks = (20 gene chunks) x (32 row tiles of 16 rows)
constexpr int GCHUNK = 1024;             // genes per block: 256 thr x 4
constexpr int NGC    = 20;               // 20 * 1024 = 20480
constexpr int JPAD   = NGC * GCHUNK;     // 20480
constexpr int ROWT   = 16;               // rows per block
constexpr int NRT    = N_SAMPLES / ROWT; // 32

// loglik tiling (round-6 shape)
constexpr int LCHUNK = 2048;             // 256 thr x 4 x 2 groups
constexpr int NBJ    = 10;               // 10 * 2048 = 20480
constexpr int NPART  = NBJ * N_SAMPLES;  // 5120 partials

constexpr int TABLE_N = 1024;            // lgamma(y+1), y in [0,1000]

// ws layout (float offsets)
constexpr size_t WS_RW    = 0;                               // r = 1/softplus(phi)  [JPAD]
constexpr size_t WS_MUP   = WS_RW    + JPAD;                 // mu padded            [JPAD]
constexpr size_t WS_BETAP = WS_MUP   + JPAD;                 // beta repacked [p][J] [P*JPAD]
constexpr size_t WS_CVEC  = WS_BETAP + (size_t)P_COV * JPAD; // r*log r - lgamma(r)  [JPAD]
constexpr size_t WS_LGYT  = WS_CVEC  + JPAD;                 // lgamma(k+1) table    [TABLE_N]
constexpr size_t WS_SACC  = WS_LGYT  + TABLE_N;              // per-row sum(Y)       [N]
constexpr size_t WS_EACC  = WS_SACC  + N_SAMPLES;            // per-row sum(exp)     [N]
constexpr size_t WS_PART  = WS_EACC  + N_SAMPLES;            // loglik partials      [NPART]
constexpr size_t WS_LOGH  = WS_PART  + NPART;                // fp16 logits [N][JPAD] (half)
constexpr size_t WS_TOTAL = WS_LOGH  + (size_t)N_SAMPLES * JPAD / 2;  // floats

__device__ inline float wave_reduce_sum(float v) {
#pragma unroll
    for (int off = 32; off > 0; off >>= 1)
        v += __shfl_down(v, off, 64);
    return v;
}

__device__ inline float block_reduce_sum(float v, float* red) {
    const int t = threadIdx.x;
    float w = wave_reduce_sum(v);
    if ((t & 63) == 0) red[t >> 6] = w;
    __syncthreads();
    float b = 0.0f;
#pragma unroll
    for (int i = 0; i < NW; ++i) b += red[i];
    return b;
}

// Stirling lgamma for z >= ~0.2. ~1e-6 rel accuracy (threshold is 2% of 1e8).
__device__ inline float lgamma_pos(float z) {
    float corr = 0.0f;
    if (z < 8.0f) {
        float p = z;
        p *= (z + 1.0f); p *= (z + 2.0f); p *= (z + 3.0f);
        p *= (z + 4.0f); p *= (z + 5.0f); p *= (z + 6.0f); p *= (z + 7.0f);
        corr = -__logf(p);
        z += 8.0f;
    }
    float lz  = __logf(z);
    float rz  = __builtin_amdgcn_rcpf(z);
    float rz2 = rz * rz;
    float ser = rz * fmaf(rz2, fmaf(rz2, 7.9365079365e-4f, -2.7777777778e-3f),
                          8.3333333333e-2f);
    return fmaf(z - 0.5f, lz, 0.91893853320467274f - z + ser + corr);
}

// ---------------------------------------------------------------------------
// Prep: padded repack + per-gene tables + zero s/E accumulators.
// ---------------------------------------------------------------------------
__global__ __launch_bounds__(BLOCK) void prep_kernel(
    const float* __restrict__ mu, const float* __restrict__ beta,
    const float* __restrict__ phi, float* __restrict__ ws) {
    const int gid = blockIdx.x * BLOCK + threadIdx.x;
    if (gid < TABLE_N) ws[WS_LGYT + gid] = lgammaf((float)gid + 1.0f);
    if (gid < N_SAMPLES) { ws[WS_SACC + gid] = 0.0f; ws[WS_EACC + gid] = 0.0f; }
    if (gid >= JPAD) return;
    if (gid < J_GENES) {
        const int j = gid;
        float ph = phi[j];
        float sp = (ph > 20.0f) ? ph : log1pf(__expf(ph));   // softplus
        float r  = 1.0f / sp;
        ws[WS_RW   + j] = r;
        ws[WS_CVEC + j] = fmaf(r, -__logf(sp), -lgammaf(r)); // r*log r - lgamma(r)
        ws[WS_MUP  + j] = (j < DIM) ? mu[j] : 0.0f;          // pivot logit = 0
#pragma unroll
        for (int p = 0; p < P_COV; ++p)
            ws[WS_BETAP + (size_t)p * JPAD + j] =
                (j < DIM) ? beta[p * DIM + j] : 0.0f;
    } else {
        ws[WS_RW   + gid] = 1.0f;
        ws[WS_CVEC + gid] = 0.0f;
        ws[WS_MUP  + gid] = 0.0f;
#pragma unroll
        for (int p = 0; p < P_COV; ++p)
            ws[WS_BETAP + (size_t)p * JPAD + gid] = 0.0f;
    }
}

// ---------------------------------------------------------------------------
// logitE: grid (NGC, NRT). Each block: 1024 genes x 16 rows.
// Per thread: 4 genes' beta held in registers, loop over 16 rows.
// Produces fp16 logits [n][j] and per-row s, E via atomics.
// ---------------------------------------------------------------------------
__global__ __launch_bounds__(BLOCK) void logitE_kernel(
    const float* __restrict__ X, const float* __restrict__ Y,
    float* __restrict__ ws) {
    const int t    = threadIdx.x;
    const int j    = blockIdx.x * GCHUNK + t * 4;
    const int row0 = blockIdx.y * ROWT;
    const bool valid = (j < J_GENES);

    __shared__ __align__(16) float xs[ROWT * P_COV];   // 16 rows x 8 covs
    __shared__ float lds_s[ROWT][NW], lds_e[ROWT][NW];
    if (t < ROWT * P_COV) xs[t] = X[row0 * P_COV + t];
    __syncthreads();

    // per-gene constants in registers (no spill: 9 float4 = 36 VGPRs)
    const float4 zero4 = make_float4(0.f, 0.f, 0.f, 0.f);
    float4 mu4 = valid ? *(const float4*)(ws + WS_MUP + j) : zero4;
    float4 b0 = valid ? *(const float4*)(ws + WS_BETAP + 0 * JPAD + j) : zero4;
    float4 b1 = valid ? *(const float4*)(ws + WS_BETAP + 1 * JPAD + j) : zero4;
    float4 b2 = valid ? *(const float4*)(ws + WS_BETAP + 2 * JPAD + j) : zero4;
    float4 b3 = valid ? *(const float4*)(ws + WS_BETAP + 3 * JPAD + j) : zero4;
    float4 b4 = valid ? *(const float4*)(ws + WS_BETAP + 4 * JPAD + j) : zero4;
    float4 b5 = valid ? *(const float4*)(ws + WS_BETAP + 5 * JPAD + j) : zero4;
    float4 b6 = valid ? *(const float4*)(ws + WS_BETAP + 6 * JPAD + j) : zero4;
    float4 b7 = valid ? *(const float4*)(ws + WS_BETAP + 7 * JPAD + j) : zero4;

    __half* logh = (__half*)(ws + WS_LOGH);

#pragma unroll 2
    for (int r = 0; r < ROWT; ++r) {
        const int n = row0 + r;
        float4 xa = *(const float4*)&xs[r * P_COV + 0];
        float4 xb = *(const float4*)&xs[r * P_COV + 4];

        float4 lg = mu4;
        lg.x = fmaf(xa.x, b0.x, lg.x); lg.y = fmaf(xa.x, b0.y, lg.y);
        lg.z = fmaf(xa.x, b0.z, lg.z); lg.w = fmaf(xa.x, b0.w, lg.w);
        lg.x = fmaf(xa.y, b1.x, lg.x); lg.y = fmaf(xa.y, b1.y, lg.y);
        lg.z = fmaf(xa.y, b1.z, lg.z); lg.w = fmaf(xa.y, b1.w, lg.w);
        lg.x = fmaf(xa.z, b2.x, lg.x); lg.y = fmaf(xa.z, b2.y, lg.y);
        lg.z = fmaf(xa.z, b2.z, lg.z); lg.w = fmaf(xa.z, b2.w, lg.w);
        lg.x = fmaf(xa.w, b3.x, lg.x); lg.y = fmaf(xa.w, b3.y, lg.y);
        lg.z = fmaf(xa.w, b3.z, lg.z); lg.w = fmaf(xa.w, b3.w, lg.w);
        lg.x = fmaf(xb.x, b4.x, lg.x); lg.y = fmaf(xb.x, b4.y, lg.y);
        lg.z = fmaf(xb.x, b4.z, lg.z); lg.w = fmaf(xb.x, b4.w, lg.w);
        lg.x = fmaf(xb.y, b5.x, lg.x); lg.y = fmaf(xb.y, b5.y, lg.y);
        lg.z = fmaf(xb.y, b5.z, lg.z); lg.w = fmaf(xb.y, b5.w, lg.w);
        lg.x = fmaf(xb.z, b6.x, lg.x); lg.y = fmaf(xb.z, b6.y, lg.y);
        lg.z = fmaf(xb.z, b6.z, lg.z); lg.w = fmaf(xb.z, b6.w, lg.w);
        lg.x = fmaf(xb.w, b7.x, lg.x); lg.y = fmaf(xb.w, b7.y, lg.y);
        lg.z = fmaf(xb.w, b7.z, lg.z); lg.w = fmaf(xb.w, b7.w, lg.w);

        float e_c = 0.0f, s_c = 0.0f;
        if (valid) {
            e_c = (__expf(lg.x) + __expf(lg.y)) + (__expf(lg.z) + __expf(lg.w));
            float4 y4 = *(const float4*)(Y + (size_t)n * J_GENES + j);
            s_c = (y4.x + y4.y) + (y4.z + y4.w);
            __half2* dst = (__half2*)(logh + (size_t)n * JPAD + j);
            dst[0] = __floats2half2_rn(lg.x, lg.y);
            dst[1] = __floats2half2_rn(lg.z, lg.w);
        }
        float es = wave_reduce_sum(e_c);
        float ss = wave_reduce_sum(s_c);
        if ((t & 63) == 0) { lds_e[r][t >> 6] = es; lds_s[r][t >> 6] = ss; }
    }
    __syncthreads();
    if (t < ROWT) {
        float es = 0.f, ss = 0.f;
#pragma unroll
        for (int w = 0; w < NW; ++w) { es += lds_e[t][w]; ss += lds_s[t][w]; }
        atomicAdd(&ws[WS_EACC + row0 + t], es);
        atomicAdd(&ws[WS_SACC + row0 + t], ss);
    }
}

// ---------------------------------------------------------------------------
// loglik: grid (NBJ, N). Per element loads y4 + fp16 logit4 + r4 only.
//   sum_j [ lgamma(y+r) - lgamma(y+1) - (y+r)*log(r+mean) + y*logit ]
// (cvec and per-row closed-form terms added in final_kernel)
// ---------------------------------------------------------------------------
__global__ __launch_bounds__(BLOCK) void loglik_kernel(
    const float* __restrict__ Y, float* __restrict__ ws) {
    const int n = blockIdx.y;
    const int t = threadIdx.x;
    const int j0 = blockIdx.x * LCHUNK + t * 4;

    __shared__ __align__(16) float tbl[TABLE_N];
    *(float4*)&tbl[t * 4] = *(const float4*)(ws + WS_LGYT + t * 4);

    const float* yrow = Y + (size_t)n * J_GENES;
    const __half* lrow = (const __half*)(ws + WS_LOGH) + (size_t)n * JPAD;

    const float s  = ws[WS_SACC + n];
    const float E  = ws[WS_EACC + n];
    const float sE = s / E;          // mean = sE * exp(logit)
    __syncthreads();                 // tbl ready

    float acc = 0.0f;
    for (int g = 0; g < 2; ++g) {
        const int j = j0 + g * (BLOCK * 4);
        if (j < J_GENES) {
            float4 y4 = *(const float4*)(yrow + j);
            float4 r4 = *(const float4*)(ws + WS_RW + j);
            const __half2* lp = (const __half2*)(lrow + j);
            float2 l01 = __half22float2(lp[0]);
            float2 l23 = __half22float2(lp[1]);
            float lgv[4] = {l01.x, l01.y, l23.x, l23.y};
#pragma unroll
            for (int e = 0; e < 4; ++e) {
                float y     = (&y4.x)[e];
                float r     = (&r4.x)[e];
                float logit = lgv[e];
                float mean  = sE * __expf(logit);
                float lrm   = __logf(r + mean);
                int   yi    = (int)(y + 0.5f);
                float lgy1  = (yi < TABLE_N) ? tbl[yi] : lgamma_pos(y + 1.0f);
                acc += lgamma_pos(y + r) - lgy1
                     + fmaf(-(y + r), lrm, y * logit);
            }
        }
    }

    __shared__ float red[NW];
    float b = block_reduce_sum(acc, red);
    if (t == 0) ws[WS_PART + (size_t)n * NBJ + blockIdx.x] = b;
}

// ---------------------------------------------------------------------------
// Final: out = sum(partials) + sum_n s_n*(log s_n - log E_n) + N * sum_j cvec.
// ---------------------------------------------------------------------------
__global__ __launch_bounds__(BLOCK) void final_kernel(
    const float* __restrict__ ws, float* __restrict__ out) {
    const int t = threadIdx.x;
    float acc = 0.0f;
    for (int i = t; i < NPART; i += BLOCK) acc += ws[WS_PART + i];
    for (int n = t; n < N_SAMPLES; n += BLOCK) {
        float s = ws[WS_SACC + n];
        float E = ws[WS_EACC + n];
        acc += s * (__logf(s) - __logf(E));
    }
    float cacc = 0.0f;
    for (int i = t; i < J_GENES; i += BLOCK) cacc += ws[WS_CVEC + i];
    acc += (float)N_SAMPLES * cacc;

    __shared__ float red[NW];
    float b = block_reduce_sum(acc, red);
    if (t == 0) out[0] = b;
}

// ---------------------------------------------------------------------------
// Fallback (ws too small): monolithic known-correct kernel, no workspace.
// ---------------------------------------------------------------------------
__global__ __launch_bounds__(256) void nb_mono(
    const float* __restrict__ mu, const float* __restrict__ beta,
    const float* __restrict__ phi, const float* __restrict__ X,
    const float* __restrict__ Y, float* __restrict__ out) {
    const int n = blockIdx.x;
    const int t = threadIdx.x;
    __shared__ float red[4];
    __shared__ float sh_s, sh_lse, sh_logs;
    float x[P_COV];
#pragma unroll
    for (int p = 0; p < P_COV; ++p) x[p] = X[n * P_COV + p];
    const float* yrow = Y + (size_t)n * J_GENES;
    float s_acc = 0.0f, e_acc = 0.0f;
    for (int j = t; j < J_GENES; j += 256) {
        float logit = 0.0f;
        if (j < DIM) {
            logit = mu[j];
#pragma unroll
            for (int p = 0; p < P_COV; ++p)
                logit = fmaf(x[p], beta[p * DIM + j], logit);
        }
        s_acc += yrow[j];
        e_acc += __expf(logit);
    }
    float v = wave_reduce_sum(s_acc);
    if ((t & 63) == 0) red[t >> 6] = v;
    __syncthreads();
    if (t == 0) { float st = red[0]+red[1]+red[2]+red[3]; sh_s = st; sh_logs = __logf(st); }
    __syncthreads();
    v = wave_reduce_sum(e_acc);
    if ((t & 63) == 0) red[t >> 6] = v;
    __syncthreads();
    if (t == 0) sh_lse = __logf(red[0]+red[1]+red[2]+red[3]);
    __syncthreads();
    const float s = sh_s, logs = sh_logs, lse = sh_lse;
    float acc = 0.0f;
    for (int j = t; j < J_GENES; j += 256) {
        float logit = 0.0f;
        if (j < DIM) {
            logit = mu[j];
#pragma unroll
            for (int p = 0; p < P_COV; ++p)
                logit = fmaf(x[p], beta[p * DIM + j], logit);
        }
        float ph = phi[j];
        float sp = (ph > 20.0f) ? ph : log1pf(__expf(ph));
        float r  = 1.0f / sp;
        float y  = yrow[j];
        float lp = logit - lse;
        float mean = s * __expf(lp);
        float lrm  = __logf(r + mean);
        acc += lgamma_pos(y + r) - lgamma_pos(r) - lgamma_pos(y + 1.0f)
             + fmaf(r, -__logf(sp) - lrm, y * ((logs + lp) - lrm));
    }
    v = wave_reduce_sum(acc);
    if ((t & 63) == 0) red[t >> 6] = v;
    __syncthreads();
    if (t == 0) atomicAdd(out, (red[0]+red[1])+(red[2]+red[3]));
}

__global__ void zero_out_kernel(float* __restrict__ out) { out[0] = 0.0f; }

// ---------------------------------------------------------------------------
extern "C" void kernel_launch(void* const* d_in, const int* in_sizes, int n_in,
                              void* d_out, int out_size, void* d_ws, size_t ws_size,
                              hipStream_t stream) {
    const float* mu   = (const float*)d_in[0];  // [DIM]
    const float* beta = (const float*)d_in[1];  // [P*DIM]
    const float* phi  = (const float*)d_in[2];  // [J]
    const float* X    = (const float*)d_in[3];  // [N,P]
    const float* Y    = (const float*)d_in[4];  // [N,J]
    float* out = (float*)d_out;
    float* ws  = (float*)d_ws;

    if (ws_size >= WS_TOTAL * sizeof(float)) {
        prep_kernel<<<JPAD / BLOCK, BLOCK, 0, stream>>>(mu, beta, phi, ws);
        logitE_kernel<<<dim3(NGC, NRT), BLOCK, 0, stream>>>(X, Y, ws);
        loglik_kernel<<<dim3(NBJ, N_SAMPLES), BLOCK, 0, stream>>>(Y, ws);
        final_kernel<<<1, BLOCK, 0, stream>>>(ws, out);
    } else {
        zero_out_kernel<<<1, 1, 0, stream>>>(out);
        nb_mono<<<N_SAMPLES, 256, 0, stream>>>(mu, beta, phi, X, Y, out);
    }
}